// Round 3
// baseline (3549.509 us; speedup 1.0000x reference)
//
#include <hip/hip_runtime.h>
#include <hip/hip_bf16.h>
#include <math.h>

#define NB 16
#define NS 4096
#define ND 1024
#define NM (NB * NS)

// workspace layout (float offsets). Proven-safe footprint <= 3.7 MB.
#define WS_T       0                            // 16*1024 floats
#define WS_SCORES  16384                        // 16*4096
#define WS_WEIGHTS (WS_SCORES + NB * NS)        // 16*4096
#define WS_SHARED  (WS_WEIGHTS + NB * NS)       // 2 MB region: wbf16 (before scores) / part (after)

typedef short v8s __attribute__((ext_vector_type(8)));
typedef float v4f __attribute__((ext_vector_type(4)));
typedef unsigned short ushort;

__device__ __forceinline__ ushort f2bf(float f) {
    __hip_bfloat16 h = __float2bfloat16(f);
    return *reinterpret_cast<ushort*>(&h);
}

__device__ __forceinline__ float fast_tanh(float x) {
    float e = __expf(2.0f * x);
    return 1.0f - 2.0f / (e + 1.0f);
}

// ---------------- kernel 0: W_in fp32 -> bf16 ----------------
__global__ __launch_bounds__(256) void convw_kernel(const float* __restrict__ W,
                                                    ushort* __restrict__ Wb) {
    int flat = blockIdx.x * 256 + threadIdx.x;
#pragma unroll
    for (int j = 0; j < 2; ++j) {
        int idx = flat + j * 131072;
        float4 v = ((const float4*)W)[idx];
        ushort4 o;
        o.x = f2bf(v.x); o.y = f2bf(v.y); o.z = f2bf(v.z); o.w = f2bf(v.w);
        ((ushort4*)Wb)[idx] = o;
    }
}

// ---------------- kernel 1: t[b][e] = b_in[e]+b_ctx[e]+context[b].W_ctx[e] ----------------
// grid (16,16): block = (e-chunk of 64, b). 4 lanes per e, K split 4x256.
__global__ __launch_bounds__(256) void tvec_kernel(const float* __restrict__ context,
                                                   const float* __restrict__ W_ctx,
                                                   const float* __restrict__ b_in,
                                                   const float* __restrict__ b_ctx,
                                                   float* __restrict__ t) {
    __shared__ float ctx[ND];
    int b = blockIdx.y;
    int tid = threadIdx.x;
    for (int i = tid; i < ND; i += 256) ctx[i] = context[b * ND + i];
    __syncthreads();
    int e = blockIdx.x * 64 + (tid >> 2);
    int kq = tid & 3;
    const float4* wr = (const float4*)(W_ctx + (size_t)e * ND + kq * 256);
    const float4* cr = (const float4*)(ctx + kq * 256);
    float acc = 0.f;
#pragma unroll 4
    for (int k = 0; k < 64; ++k) {
        float4 w = wr[k];
        float4 c = cr[k];
        acc += c.x * w.x + c.y * w.y + c.z * w.z + c.w * w.w;
    }
    acc += __shfl_xor(acc, 1);
    acc += __shfl_xor(acc, 2);
    if (kq == 0) t[b * ND + e] = acc + b_in[e] + b_ctx[e];
}

// ---------------- kernel 2: scores via bf16 MFMA, K-quartered staging ----------------
// 64 rows/block, 512 threads (8 waves), wave owns 128 e-cols (2 passes x 64).
// A staged per K-quarter (32 KB LDS) -> 4 blocks/CU. B prefetched 1-deep from L2.
__global__ __launch_bounds__(512, 6) void scores_mfma_kernel(const float* __restrict__ x,
                                                             const ushort* __restrict__ Wb,
                                                             const float* __restrict__ t,
                                                             const float* __restrict__ w_att,
                                                             float* __restrict__ scores) {
    __shared__ ushort As[64 * 256];    // 32 KB, elem ^= (row&7)<<3 (16B swizzle)
    __shared__ float red[8][64];

    int tid = threadIdx.x;
    int row0 = blockIdx.x * 64;
    int b = row0 >> 12;

    int w = tid >> 6;
    int l = tid & 63;
    int l15 = l & 15;
    int kofs = (l >> 4) * 8;
    int xorv = (l & 7) << 3;
    int n0base = w * 128;

    v4f acc[2][4][4];
#pragma unroll
    for (int p = 0; p < 2; ++p)
#pragma unroll
        for (int i = 0; i < 4; ++i)
#pragma unroll
            for (int j = 0; j < 4; ++j) acc[p][i][j] = (v4f)(0.f);

    int c4 = tid & 63;            // float4 col within the 64-wide quarter
    int rb = tid >> 6;            // row base 0..7
    const float4* xf4 = (const float4*)x;

    for (int kh = 0; kh < 4; ++kh) {
        if (kh) __syncthreads();
        // ---- stage A quarter: 64 rows x 256 cols fp32 -> bf16 LDS ----
#pragma unroll
        for (int i = 0; i < 8; ++i) {
            int r = i * 8 + rb;
            float4 v = xf4[(size_t)(row0 + r) * 256 + kh * 64 + c4];
            ushort4 o;
            o.x = f2bf(v.x); o.y = f2bf(v.y); o.z = f2bf(v.z); o.w = f2bf(v.w);
            int swz = (c4 * 4) ^ ((r & 7) << 3);
            *(ushort4*)&As[r * 256 + swz] = o;
        }
        __syncthreads();

#pragma unroll
        for (int pass = 0; pass < 2; ++pass) {
            int n0 = n0base + pass * 64;
            const ushort* bp0 = Wb + (size_t)(n0 + l15) * ND + kh * 256 + kofs;
            v8s bc[4], bn[4];
#pragma unroll
            for (int nf = 0; nf < 4; ++nf) bc[nf] = *(const v8s*)(bp0 + nf * 16 * ND);
#pragma unroll
            for (int ks = 0; ks < 8; ++ks) {
                v8s af[4];
                int elem = (ks * 32 + kofs) ^ xorv;
#pragma unroll
                for (int mf = 0; mf < 4; ++mf)
                    af[mf] = *(const v8s*)&As[(mf * 16 + l15) * 256 + elem];
                if (ks < 7) {
#pragma unroll
                    for (int nf = 0; nf < 4; ++nf)
                        bn[nf] = *(const v8s*)(bp0 + nf * 16 * ND + (ks + 1) * 32);
                }
#pragma unroll
                for (int mf = 0; mf < 4; ++mf)
#pragma unroll
                    for (int nf = 0; nf < 4; ++nf)
                        acc[pass][mf][nf] = __builtin_amdgcn_mfma_f32_16x16x32_bf16(
                            af[mf], bc[nf], acc[pass][mf][nf], 0, 0, 0);
#pragma unroll
                for (int nf = 0; nf < 4; ++nf) bc[nf] = bn[nf];
            }
        }
    }

    // ---- epilogue: tanh + dot(w_att), reduce over e ----
    float s[4][4];
#pragma unroll
    for (int i = 0; i < 4; ++i)
#pragma unroll
        for (int j = 0; j < 4; ++j) s[i][j] = 0.f;

#pragma unroll
    for (int pass = 0; pass < 2; ++pass)
#pragma unroll
        for (int nf = 0; nf < 4; ++nf) {
            int e = n0base + pass * 64 + nf * 16 + l15;
            float tv = t[b * ND + e];
            float wv = w_att[e];
#pragma unroll
            for (int mf = 0; mf < 4; ++mf)
#pragma unroll
                for (int r = 0; r < 4; ++r)
                    s[mf][r] += fast_tanh(acc[pass][mf][nf][r] + tv) * wv;
        }

#pragma unroll
    for (int mf = 0; mf < 4; ++mf)
#pragma unroll
        for (int r = 0; r < 4; ++r) {
            float v = s[mf][r];
            v += __shfl_xor(v, 1);
            v += __shfl_xor(v, 2);
            v += __shfl_xor(v, 4);
            v += __shfl_xor(v, 8);
            s[mf][r] = v;
        }
    if (l15 == 0) {
#pragma unroll
        for (int mf = 0; mf < 4; ++mf)
#pragma unroll
            for (int r = 0; r < 4; ++r)
                red[w][mf * 16 + (l >> 4) * 4 + r] = s[mf][r];
    }
    __syncthreads();
    if (tid < 64) {
        float v = 0.f;
#pragma unroll
        for (int ww = 0; ww < 8; ++ww) v += red[ww][tid];
        scores[(size_t)b * NS + (row0 & (NS - 1)) + tid] = v;
    }
}

// ---------------- kernel 3: softmax over S per batch ----------------
__global__ __launch_bounds__(256) void softmax_kernel(const float* __restrict__ scores,
                                                      float* __restrict__ weights) {
    int b = blockIdx.x;
    int tid = threadIdx.x;
    float v[16];
    float lmax = -1e30f;
#pragma unroll
    for (int i = 0; i < 16; ++i) {
        v[i] = scores[b * NS + tid + i * 256];
        lmax = fmaxf(lmax, v[i]);
    }
#pragma unroll
    for (int off = 32; off >= 1; off >>= 1) lmax = fmaxf(lmax, __shfl_xor(lmax, off));
    __shared__ float redm[4];
    int wave = tid >> 6;
    if ((tid & 63) == 0) redm[wave] = lmax;
    __syncthreads();
    float bmax = fmaxf(fmaxf(redm[0], redm[1]), fmaxf(redm[2], redm[3]));

    float lsum = 0.f;
#pragma unroll
    for (int i = 0; i < 16; ++i) {
        v[i] = expf(v[i] - bmax);
        lsum += v[i];
    }
#pragma unroll
    for (int off = 32; off >= 1; off >>= 1) lsum += __shfl_xor(lsum, off);
    __shared__ float reds[4];
    if ((tid & 63) == 0) reds[wave] = lsum;
    __syncthreads();
    float inv = 1.0f / (reds[0] + reds[1] + reds[2] + reds[3]);
#pragma unroll
    for (int i = 0; i < 16; ++i) weights[b * NS + tid + i * 256] = v[i] * inv;
}

// ---------------- kernel 4: partial weighted sums over 32 s-chunks ----------------
__global__ __launch_bounds__(256) void wsum_kernel(const float* __restrict__ x,
                                                   const float* __restrict__ w,
                                                   float* __restrict__ part) {
    int sc = blockIdx.x, b = blockIdx.y;
    int d0 = threadIdx.x * 4;
    const float* xb = x + ((size_t)b * NS + sc * 128) * ND;
    const float* wb = w + b * NS + sc * 128;
    float4 acc = {0.f, 0.f, 0.f, 0.f};
    for (int ss = 0; ss < 128; ++ss) {
        float wv = wb[ss];
        float4 xv = *(const float4*)&xb[(size_t)ss * ND + d0];
        acc.x += wv * xv.x;
        acc.y += wv * xv.y;
        acc.z += wv * xv.z;
        acc.w += wv * xv.w;
    }
    *(float4*)&part[(size_t)(b * 32 + sc) * ND + d0] = acc;
}

// ---------------- kernel 5: reduce partials -> out ----------------
__global__ __launch_bounds__(256) void reduce_kernel(const float* __restrict__ part,
                                                     float* __restrict__ out) {
    int b = blockIdx.x;
    int d0 = threadIdx.x * 4;
    float4 acc = {0.f, 0.f, 0.f, 0.f};
#pragma unroll
    for (int sc = 0; sc < 32; ++sc) {
        float4 v = *(const float4*)&part[(size_t)(b * 32 + sc) * ND + d0];
        acc.x += v.x;
        acc.y += v.y;
        acc.z += v.z;
        acc.w += v.w;
    }
    *(float4*)&out[b * ND + d0] = acc;
}

extern "C" void kernel_launch(void* const* d_in, const int* in_sizes, int n_in,
                              void* d_out, int out_size, void* d_ws, size_t ws_size,
                              hipStream_t stream) {
    const float* x       = (const float*)d_in[0];
    const float* context = (const float*)d_in[1];
    const float* W_in    = (const float*)d_in[2];
    const float* b_in    = (const float*)d_in[3];
    const float* W_ctx   = (const float*)d_in[4];
    const float* b_ctx   = (const float*)d_in[5];
    const float* w_att   = (const float*)d_in[6];
    // b_att (d_in[7]): softmax is shift-invariant; it cancels.

    float* ws      = (float*)d_ws;
    float* t       = ws + WS_T;
    float* scores  = ws + WS_SCORES;
    float* weights = ws + WS_WEIGHTS;
    ushort* wbf16  = (ushort*)(ws + WS_SHARED);  // live: convw -> scores
    float* part    = ws + WS_SHARED;             // live: wsum -> reduce (overlays wbf16)
    float* out     = (float*)d_out;

    convw_kernel<<<dim3(512), 256, 0, stream>>>(W_in, wbf16);
    tvec_kernel<<<dim3(16, NB), 256, 0, stream>>>(context, W_ctx, b_in, b_ctx, t);
    scores_mfma_kernel<<<dim3(NM / 64), 512, 0, stream>>>(x, wbf16, t, w_att, scores);
    softmax_kernel<<<dim3(NB), 256, 0, stream>>>(scores, weights);
    wsum_kernel<<<dim3(32, NB), 256, 0, stream>>>(x, weights, part);
    reduce_kernel<<<dim3(NB), 256, 0, stream>>>(part, out);
}

// Round 4
// 368.284 us; speedup vs baseline: 9.6380x; 9.6380x over previous
//
#include <hip/hip_runtime.h>
#include <hip/hip_bf16.h>
#include <math.h>

#define NB 16
#define NS 4096
#define ND 1024
#define NM (NB * NS)

// workspace layout (float offsets). Proven-safe footprint <= 3.7 MB.
#define WS_T       0                            // 16*1024 floats
#define WS_SCORES  16384                        // 16*4096
#define WS_WEIGHTS (WS_SCORES + NB * NS)        // 16*4096
#define WS_SHARED  (WS_WEIGHTS + NB * NS)       // 2 MB region: wbf16 (before scores) / part (after)

typedef short v8s __attribute__((ext_vector_type(8)));
typedef float v4f __attribute__((ext_vector_type(4)));
typedef unsigned short ushort;

__device__ __forceinline__ ushort f2bf(float f) {
    __hip_bfloat16 h = __float2bfloat16(f);
    return *reinterpret_cast<ushort*>(&h);
}

__device__ __forceinline__ float fast_tanh(float x) {
    float e = __expf(2.0f * x);
    return 1.0f - 2.0f / (e + 1.0f);
}

// ---------------- kernel 0: W_in fp32 -> bf16 ----------------
__global__ __launch_bounds__(256) void convw_kernel(const float* __restrict__ W,
                                                    ushort* __restrict__ Wb) {
    int flat = blockIdx.x * 256 + threadIdx.x;
#pragma unroll
    for (int j = 0; j < 2; ++j) {
        int idx = flat + j * 131072;
        float4 v = ((const float4*)W)[idx];
        ushort4 o;
        o.x = f2bf(v.x); o.y = f2bf(v.y); o.z = f2bf(v.z); o.w = f2bf(v.w);
        ((ushort4*)Wb)[idx] = o;
    }
}

// ---------------- kernel 1: t[b][e] = b_in[e]+b_ctx[e]+context[b].W_ctx[e] ----------------
__global__ __launch_bounds__(256) void tvec_kernel(const float* __restrict__ context,
                                                   const float* __restrict__ W_ctx,
                                                   const float* __restrict__ b_in,
                                                   const float* __restrict__ b_ctx,
                                                   float* __restrict__ t) {
    __shared__ float ctx[ND];
    int b = blockIdx.y;
    int tid = threadIdx.x;
    for (int i = tid; i < ND; i += 256) ctx[i] = context[b * ND + i];
    __syncthreads();
    int e = blockIdx.x * 64 + (tid >> 2);
    int kq = tid & 3;
    const float4* wr = (const float4*)(W_ctx + (size_t)e * ND + kq * 256);
    const float4* cr = (const float4*)(ctx + kq * 256);
    float acc = 0.f;
#pragma unroll 4
    for (int k = 0; k < 64; ++k) {
        float4 w = wr[k];
        float4 c = cr[k];
        acc += c.x * w.x + c.y * w.y + c.z * w.z + c.w * w.w;
    }
    acc += __shfl_xor(acc, 1);
    acc += __shfl_xor(acc, 2);
    if (kq == 0) t[b * ND + e] = acc + b_in[e] + b_ctx[e];
}

// ---------------- kernel 2: scores via bf16 MFMA, 2-phase double-buffered ----------------
// 64 rows/block, 512 thr (8 waves), wave owns 128 e-cols (2 passes x 64, pass-inner acc).
// K in 4 stages of 256; LDS dbuf 2x32KB; next-stage x-loads issued before compute (T14);
// one barrier per stage. B frags from L2, 1-deep prefetch (pass 0).
__global__ __launch_bounds__(512) void scores_mfma_kernel(const float* __restrict__ x,
                                                          const ushort* __restrict__ Wb,
                                                          const float* __restrict__ t,
                                                          const float* __restrict__ w_att,
                                                          float* __restrict__ scores) {
    __shared__ ushort As[2][64 * 256];   // 64 KB dbuf, elem ^= (row&7)<<3 (16B swizzle)
    __shared__ float red[8][64];

    int tid = threadIdx.x;
    int row0 = blockIdx.x * 64;
    int b = row0 >> 12;
    const float4* xf4 = (const float4*)x;

    // staging map: 8 threads/row, 8 float4 each
    int sr = tid >> 3;
    int sc = tid & 7;
    int swzbase = (sr & 7) << 3;

    float4 nx[8];
#pragma unroll
    for (int j = 0; j < 8; ++j)
        nx[j] = xf4[(size_t)(row0 + sr) * 256 + sc + j * 8];
#pragma unroll
    for (int j = 0; j < 8; ++j) {
        int c4 = sc + j * 8;
        ushort4 o;
        o.x = f2bf(nx[j].x); o.y = f2bf(nx[j].y); o.z = f2bf(nx[j].z); o.w = f2bf(nx[j].w);
        *(ushort4*)&As[0][sr * 256 + ((c4 * 4) ^ swzbase)] = o;
    }
    __syncthreads();

    int w = tid >> 6;
    int l = tid & 63;
    int l15 = l & 15;
    int kofs = (l >> 4) * 8;
    int xorv = (l & 7) << 3;
    int n0 = w * 128;

    v4f acc[2][4][4];
#pragma unroll
    for (int p = 0; p < 2; ++p)
#pragma unroll
        for (int i = 0; i < 4; ++i)
#pragma unroll
            for (int j = 0; j < 4; ++j) acc[p][i][j] = (v4f)(0.f);

    const ushort* bbase0 = Wb + (size_t)(n0 + l15) * ND + kofs;
    const ushort* bbase1 = bbase0 + (size_t)64 * ND;

#pragma unroll
    for (int kh = 0; kh < 4; ++kh) {
        // issue next stage's global loads early (hide under compute)
        if (kh < 3) {
#pragma unroll
            for (int j = 0; j < 8; ++j)
                nx[j] = xf4[(size_t)(row0 + sr) * 256 + (kh + 1) * 64 + sc + j * 8];
        }
        const ushort* Ab = &As[kh & 1][0];
        int kb = kh * 256;

        v8s b0c[4], b0n[4], b1[4];
#pragma unroll
        for (int nf = 0; nf < 4; ++nf) b0c[nf] = *(const v8s*)(bbase0 + (size_t)nf * 16 * ND + kb);

#pragma unroll
        for (int ks = 0; ks < 8; ++ks) {
            int kk = kb + ks * 32;
            int elem = (ks * 32 + kofs) ^ xorv;
            v8s af[4];
#pragma unroll
            for (int mf = 0; mf < 4; ++mf)
                af[mf] = *(const v8s*)&Ab[(mf * 16 + l15) * 256 + elem];
#pragma unroll
            for (int nf = 0; nf < 4; ++nf)
                b1[nf] = *(const v8s*)(bbase1 + (size_t)nf * 16 * ND + kk);
            if (ks < 7) {
#pragma unroll
                for (int nf = 0; nf < 4; ++nf)
                    b0n[nf] = *(const v8s*)(bbase0 + (size_t)nf * 16 * ND + kk + 32);
            }
#pragma unroll
            for (int mf = 0; mf < 4; ++mf)
#pragma unroll
                for (int nf = 0; nf < 4; ++nf)
                    acc[0][mf][nf] = __builtin_amdgcn_mfma_f32_16x16x32_bf16(
                        af[mf], b0c[nf], acc[0][mf][nf], 0, 0, 0);
#pragma unroll
            for (int mf = 0; mf < 4; ++mf)
#pragma unroll
                for (int nf = 0; nf < 4; ++nf)
                    acc[1][mf][nf] = __builtin_amdgcn_mfma_f32_16x16x32_bf16(
                        af[mf], b1[nf], acc[1][mf][nf], 0, 0, 0);
#pragma unroll
            for (int nf = 0; nf < 4; ++nf) b0c[nf] = b0n[nf];
        }

        // write next stage into the other buffer; single barrier per stage
        if (kh < 3) {
#pragma unroll
            for (int j = 0; j < 8; ++j) {
                int c4 = sc + j * 8;
                ushort4 o;
                o.x = f2bf(nx[j].x); o.y = f2bf(nx[j].y); o.z = f2bf(nx[j].z); o.w = f2bf(nx[j].w);
                *(ushort4*)&As[(kh + 1) & 1][sr * 256 + ((c4 * 4) ^ swzbase)] = o;
            }
            __syncthreads();
        }
    }

    // ---- epilogue: tanh + dot(w_att), reduce over e ----
    float s[4][4];
#pragma unroll
    for (int i = 0; i < 4; ++i)
#pragma unroll
        for (int j = 0; j < 4; ++j) s[i][j] = 0.f;

#pragma unroll
    for (int pass = 0; pass < 2; ++pass)
#pragma unroll
        for (int nf = 0; nf < 4; ++nf) {
            int e = n0 + pass * 64 + nf * 16 + l15;
            float tv = t[b * ND + e];
            float wv = w_att[e];
#pragma unroll
            for (int mf = 0; mf < 4; ++mf)
#pragma unroll
                for (int r = 0; r < 4; ++r)
                    s[mf][r] += fast_tanh(acc[pass][mf][nf][r] + tv) * wv;
        }

#pragma unroll
    for (int mf = 0; mf < 4; ++mf)
#pragma unroll
        for (int r = 0; r < 4; ++r) {
            float v = s[mf][r];
            v += __shfl_xor(v, 1);
            v += __shfl_xor(v, 2);
            v += __shfl_xor(v, 4);
            v += __shfl_xor(v, 8);
            s[mf][r] = v;
        }
    if (l15 == 0) {
#pragma unroll
        for (int mf = 0; mf < 4; ++mf)
#pragma unroll
            for (int r = 0; r < 4; ++r)
                red[w][mf * 16 + (l >> 4) * 4 + r] = s[mf][r];
    }
    __syncthreads();
    if (tid < 64) {
        float v = 0.f;
#pragma unroll
        for (int ww = 0; ww < 8; ++ww) v += red[ww][tid];
        scores[(size_t)b * NS + (row0 & (NS - 1)) + tid] = v;
    }
}

// ---------------- kernel 3: softmax over S per batch ----------------
__global__ __launch_bounds__(256) void softmax_kernel(const float* __restrict__ scores,
                                                      float* __restrict__ weights) {
    int b = blockIdx.x;
    int tid = threadIdx.x;
    float v[16];
    float lmax = -1e30f;
#pragma unroll
    for (int i = 0; i < 16; ++i) {
        v[i] = scores[b * NS + tid + i * 256];
        lmax = fmaxf(lmax, v[i]);
    }
#pragma unroll
    for (int off = 32; off >= 1; off >>= 1) lmax = fmaxf(lmax, __shfl_xor(lmax, off));
    __shared__ float redm[4];
    int wave = tid >> 6;
    if ((tid & 63) == 0) redm[wave] = lmax;
    __syncthreads();
    float bmax = fmaxf(fmaxf(redm[0], redm[1]), fmaxf(redm[2], redm[3]));

    float lsum = 0.f;
#pragma unroll
    for (int i = 0; i < 16; ++i) {
        v[i] = expf(v[i] - bmax);
        lsum += v[i];
    }
#pragma unroll
    for (int off = 32; off >= 1; off >>= 1) lsum += __shfl_xor(lsum, off);
    __shared__ float reds[4];
    if ((tid & 63) == 0) reds[wave] = lsum;
    __syncthreads();
    float inv = 1.0f / (reds[0] + reds[1] + reds[2] + reds[3]);
#pragma unroll
    for (int i = 0; i < 16; ++i) weights[b * NS + tid + i * 256] = v[i] * inv;
}

// ---------------- kernel 4: partial weighted sums over 32 s-chunks ----------------
__global__ __launch_bounds__(256) void wsum_kernel(const float* __restrict__ x,
                                                   const float* __restrict__ w,
                                                   float* __restrict__ part) {
    int sc = blockIdx.x, b = blockIdx.y;
    int d0 = threadIdx.x * 4;
    const float* xb = x + ((size_t)b * NS + sc * 128) * ND;
    const float* wb = w + b * NS + sc * 128;
    float4 acc = {0.f, 0.f, 0.f, 0.f};
    for (int ss = 0; ss < 128; ++ss) {
        float wv = wb[ss];
        float4 xv = *(const float4*)&xb[(size_t)ss * ND + d0];
        acc.x += wv * xv.x;
        acc.y += wv * xv.y;
        acc.z += wv * xv.z;
        acc.w += wv * xv.w;
    }
    *(float4*)&part[(size_t)(b * 32 + sc) * ND + d0] = acc;
}

// ---------------- kernel 5: reduce partials -> out ----------------
__global__ __launch_bounds__(256) void reduce_kernel(const float* __restrict__ part,
                                                     float* __restrict__ out) {
    int b = blockIdx.x;
    int d0 = threadIdx.x * 4;
    float4 acc = {0.f, 0.f, 0.f, 0.f};
#pragma unroll
    for (int sc = 0; sc < 32; ++sc) {
        float4 v = *(const float4*)&part[(size_t)(b * 32 + sc) * ND + d0];
        acc.x += v.x;
        acc.y += v.y;
        acc.z += v.z;
        acc.w += v.w;
    }
    *(float4*)&out[b * ND + d0] = acc;
}

extern "C" void kernel_launch(void* const* d_in, const int* in_sizes, int n_in,
                              void* d_out, int out_size, void* d_ws, size_t ws_size,
                              hipStream_t stream) {
    const float* x       = (const float*)d_in[0];
    const float* context = (const float*)d_in[1];
    const float* W_in    = (const float*)d_in[2];
    const float* b_in    = (const float*)d_in[3];
    const float* W_ctx   = (const float*)d_in[4];
    const float* b_ctx   = (const float*)d_in[5];
    const float* w_att   = (const float*)d_in[6];
    // b_att (d_in[7]): softmax is shift-invariant; it cancels.

    float* ws      = (float*)d_ws;
    float* t       = ws + WS_T;
    float* scores  = ws + WS_SCORES;
    float* weights = ws + WS_WEIGHTS;
    ushort* wbf16  = (ushort*)(ws + WS_SHARED);  // live: convw -> scores
    float* part    = ws + WS_SHARED;             // live: wsum -> reduce (overlays wbf16)
    float* out     = (float*)d_out;

    convw_kernel<<<dim3(512), 256, 0, stream>>>(W_in, wbf16);
    tvec_kernel<<<dim3(16, NB), 256, 0, stream>>>(context, W_ctx, b_in, b_ctx, t);
    scores_mfma_kernel<<<dim3(NM / 64), 512, 0, stream>>>(x, wbf16, t, w_att, scores);
    softmax_kernel<<<dim3(NB), 256, 0, stream>>>(scores, weights);
    wsum_kernel<<<dim3(32, NB), 256, 0, stream>>>(x, weights, part);
    reduce_kernel<<<dim3(NB), 256, 0, stream>>>(part, out);
}